// Round 3
// baseline (5065.601 us; speedup 1.0000x reference)
//
#include <hip/hip_runtime.h>
#include <math.h>

#define TT 35
#define BB 64
#define EMB 1500
#define HID 1500
#define VOCAB 10000
#define KT 3008          // EMB+HID padded to x32
#define KI 94            // KT/32
#define KLP 1504         // HID padded to x32 (logits K)
#define NBLK 157         // vocab n-blocks of 64
#define FORGET_BIAS 1.0f

typedef __bf16 bf16x8 __attribute__((ext_vector_type(8)));
typedef float f32x4 __attribute__((ext_vector_type(4)));

__device__ __forceinline__ unsigned short f2bf(float f) {
    unsigned int u = __builtin_bit_cast(unsigned int, f);
    u += 0x7fffu + ((u >> 16) & 1u);           // RNE
    return (unsigned short)(u >> 16);
}
__device__ __forceinline__ float sigmoidf_(float x) { return 1.0f / (1.0f + expf(-x)); }

#define LD8(p, off) (*(const bf16x8*)((p) + (off)))

// ---- W (K x N fp32) -> WT (N x KP bf16), zero-fill k in [K,KP) ----
__global__ __launch_bounds__(256) void convT(const float* __restrict__ W,
                                             unsigned short* __restrict__ WT,
                                             int K, int N, int KP) {
    __shared__ float tile[32][33];
    int tx = threadIdx.x, ty = threadIdx.y;    // 32 x 8
    int n0 = blockIdx.x * 32, k0 = blockIdx.y * 32;
#pragma unroll
    for (int i = 0; i < 4; ++i) {
        int k = k0 + ty + 8 * i, n = n0 + tx;
        tile[ty + 8 * i][tx] = (k < K && n < N) ? W[(size_t)k * N + n] : 0.f;
    }
    __syncthreads();
#pragma unroll
    for (int i = 0; i < 4; ++i) {
        int n = n0 + ty + 8 * i, k = k0 + tx;
        if (n < N) WT[(size_t)n * KP + k] = f2bf(tile[tx][ty + 8 * i]);
    }
}

// ---- embedding gather -> bf16 into per-step A0 buffers (cols 0..1499) ----
__global__ __launch_bounds__(256) void embed_kernel(const int* __restrict__ x,
                                                    const float* __restrict__ emb,
                                                    unsigned short* __restrict__ A0) {
    int tok = blockIdx.x;                       // t*BB + b (t-major)
    int v = x[tok];
    const float* src = emb + (size_t)v * EMB;
    unsigned short* dst = A0 + (size_t)tok * KT;
    for (int i = threadIdx.x; i < EMB; i += 256) dst[i] = f2bf(src[i]);
}

// ---- fused LSTM step with depth-2 register ping-pong prefetch ----
// grid 94 (16 hidden cols each), block 1024 = 16 waves = 4 m-tiles x 4 k-groups
__global__ __launch_bounds__(1024) void lstm_fused(const unsigned short* __restrict__ A,   // 64 x KT
                                                   const unsigned short* __restrict__ WT,  // 6000 x KT
                                                   const float* __restrict__ bias,         // 6000
                                                   float* __restrict__ cst,                // 64 x HID
                                                   unsigned short* __restrict__ d1, int s1,
                                                   unsigned short* __restrict__ d2, int s2) {
    __shared__ float red[16][64][17];
    int tid = threadIdx.x;
    int wv = tid >> 6, lane = tid & 63;
    int mt = wv & 3, kg = wv >> 2;
    int quad = lane >> 4, l16 = lane & 15;
    int col = blockIdx.x * 16 + l16;

    f32x4 acc0 = {0.f,0.f,0.f,0.f}, acc1 = acc0, acc2 = acc0, acc3 = acc0;

    int it0 = (KI * kg) >> 2, it1 = (KI * (kg + 1)) >> 2;
    int n_it = it1 - it0;                       // 23 or 24 (>= 2)

    const unsigned short* apb = A + (size_t)(mt * 16 + l16) * KT + quad * 8 + it0 * 32;
    int n3 = 3 * HID + col; if (n3 > 5999) n3 = 5999;   // clamp pad lanes (o gate)
    const unsigned short* bpb0 = WT + (size_t)(col) * KT + quad * 8 + it0 * 32;
    const unsigned short* bpb1 = WT + (size_t)(HID + col) * KT + quad * 8 + it0 * 32;
    const unsigned short* bpb2 = WT + (size_t)(2 * HID + col) * KT + quad * 8 + it0 * 32;
    const unsigned short* bpb3 = WT + (size_t)n3 * KT + quad * 8 + it0 * 32;

    bf16x8 aC = LD8(apb, 0), b0C = LD8(bpb0, 0), b1C = LD8(bpb1, 0), b2C = LD8(bpb2, 0), b3C = LD8(bpb3, 0);
    bf16x8 aN = LD8(apb, 32), b0N = LD8(bpb0, 32), b1N = LD8(bpb1, 32), b2N = LD8(bpb2, 32), b3N = LD8(bpb3, 32);

    int i = 0;
    for (; i + 2 < n_it; i += 2) {
        acc0 = __builtin_amdgcn_mfma_f32_16x16x32_bf16(aC, b0C, acc0, 0, 0, 0);
        acc1 = __builtin_amdgcn_mfma_f32_16x16x32_bf16(aC, b1C, acc1, 0, 0, 0);
        acc2 = __builtin_amdgcn_mfma_f32_16x16x32_bf16(aC, b2C, acc2, 0, 0, 0);
        acc3 = __builtin_amdgcn_mfma_f32_16x16x32_bf16(aC, b3C, acc3, 0, 0, 0);
        int o = (i + 2) * 32;
        aC = LD8(apb, o); b0C = LD8(bpb0, o); b1C = LD8(bpb1, o); b2C = LD8(bpb2, o); b3C = LD8(bpb3, o);
        acc0 = __builtin_amdgcn_mfma_f32_16x16x32_bf16(aN, b0N, acc0, 0, 0, 0);
        acc1 = __builtin_amdgcn_mfma_f32_16x16x32_bf16(aN, b1N, acc1, 0, 0, 0);
        acc2 = __builtin_amdgcn_mfma_f32_16x16x32_bf16(aN, b2N, acc2, 0, 0, 0);
        acc3 = __builtin_amdgcn_mfma_f32_16x16x32_bf16(aN, b3N, acc3, 0, 0, 0);
        if (i + 3 < n_it) {
            int o2 = (i + 3) * 32;
            aN = LD8(apb, o2); b0N = LD8(bpb0, o2); b1N = LD8(bpb1, o2); b2N = LD8(bpb2, o2); b3N = LD8(bpb3, o2);
        }
    }
    acc0 = __builtin_amdgcn_mfma_f32_16x16x32_bf16(aC, b0C, acc0, 0, 0, 0);
    acc1 = __builtin_amdgcn_mfma_f32_16x16x32_bf16(aC, b1C, acc1, 0, 0, 0);
    acc2 = __builtin_amdgcn_mfma_f32_16x16x32_bf16(aC, b2C, acc2, 0, 0, 0);
    acc3 = __builtin_amdgcn_mfma_f32_16x16x32_bf16(aC, b3C, acc3, 0, 0, 0);
    if (i + 1 < n_it) {
        acc0 = __builtin_amdgcn_mfma_f32_16x16x32_bf16(aN, b0N, acc0, 0, 0, 0);
        acc1 = __builtin_amdgcn_mfma_f32_16x16x32_bf16(aN, b1N, acc1, 0, 0, 0);
        acc2 = __builtin_amdgcn_mfma_f32_16x16x32_bf16(aN, b2N, acc2, 0, 0, 0);
        acc3 = __builtin_amdgcn_mfma_f32_16x16x32_bf16(aN, b3N, acc3, 0, 0, 0);
    }

#pragma unroll
    for (int r = 0; r < 4; ++r) {
        red[wv][lane][r]      = acc0[r];
        red[wv][lane][4 + r]  = acc1[r];
        red[wv][lane][8 + r]  = acc2[r];
        red[wv][lane][12 + r] = acc3[r];
    }
    __syncthreads();
    if (kg == 0) {
#pragma unroll
        for (int k2 = 1; k2 < 4; ++k2)
#pragma unroll
            for (int r = 0; r < 4; ++r) {
                acc0[r] += red[k2 * 4 + mt][lane][r];
                acc1[r] += red[k2 * 4 + mt][lane][4 + r];
                acc2[r] += red[k2 * 4 + mt][lane][8 + r];
                acc3[r] += red[k2 * 4 + mt][lane][12 + r];
            }
        if (col < HID) {
            float bi = bias[col], bj = bias[HID + col];
            float bf_ = bias[2 * HID + col], bo = bias[3 * HID + col];
#pragma unroll
            for (int r = 0; r < 4; ++r) {
                int row = mt * 16 + quad * 4 + r;
                float zi = acc0[r] + bi;
                float zj = acc1[r] + bj;
                float zf = acc2[r] + bf_;
                float zo = acc3[r] + bo;
                int ci = row * HID + col;
                float cn = cst[ci] * sigmoidf_(zf + FORGET_BIAS) + sigmoidf_(zi) * tanhf(zj);
                float hn = tanhf(cn) * sigmoidf_(zo);
                cst[ci] = cn;
                unsigned short hb = f2bf(hn);
                d1[(size_t)row * s1 + col] = hb;
                if (d2) d2[(size_t)row * s2 + col] = hb;
            }
        }
    }
}

// ---- flash logits+NLL: per block = 64 vocab cols x 320 rows; writes (max,sumexp) partials ----
// grid (157, 7), block 256 = 4 waves; wave does 5 m-subtiles of 16 rows
__global__ __launch_bounds__(256) void logits_flash(const unsigned short* __restrict__ A,   // 2240 x KLP
                                                    const unsigned short* __restrict__ WT,  // 10000 x KLP
                                                    const float* __restrict__ sb,
                                                    const int* __restrict__ y,
                                                    float2* __restrict__ partials,          // [2240][157]
                                                    float* __restrict__ tgtlog) {           // [2240]
    int tid = threadIdx.x;
    int wv = tid >> 6, lane = tid & 63;
    int quad = lane >> 4, l16 = lane & 15;
    int nb = blockIdx.x, mc = blockIdx.y;
    int n0 = nb * 64;

    int colv[4]; float bs[4];
    const unsigned short* bpb[4];
#pragma unroll
    for (int s = 0; s < 4; ++s) {
        int c = n0 + s * 16 + l16;
        colv[s] = c;
        int cc = (c < VOCAB) ? c : (VOCAB - 1);
        bpb[s] = WT + (size_t)cc * KLP + quad * 8;
        bs[s] = sb[cc];
    }

    for (int ms = 0; ms < 5; ++ms) {
        int row_base = mc * 320 + ms * 64 + wv * 16;
        const unsigned short* apb = A + (size_t)(row_base + l16) * KLP + quad * 8;
        f32x4 a0 = {0.f,0.f,0.f,0.f}, a1 = a0, a2 = a0, a3 = a0;

        bf16x8 aC = LD8(apb, 0);
        bf16x8 b0C = LD8(bpb[0], 0), b1C = LD8(bpb[1], 0), b2C = LD8(bpb[2], 0), b3C = LD8(bpb[3], 0);
        bf16x8 aN = LD8(apb, 32);
        bf16x8 b0N = LD8(bpb[0], 32), b1N = LD8(bpb[1], 32), b2N = LD8(bpb[2], 32), b3N = LD8(bpb[3], 32);

        int i = 0;
        for (; i + 2 < KLP / 32; i += 2) {
            a0 = __builtin_amdgcn_mfma_f32_16x16x32_bf16(aC, b0C, a0, 0, 0, 0);
            a1 = __builtin_amdgcn_mfma_f32_16x16x32_bf16(aC, b1C, a1, 0, 0, 0);
            a2 = __builtin_amdgcn_mfma_f32_16x16x32_bf16(aC, b2C, a2, 0, 0, 0);
            a3 = __builtin_amdgcn_mfma_f32_16x16x32_bf16(aC, b3C, a3, 0, 0, 0);
            int o = (i + 2) * 32;
            aC = LD8(apb, o); b0C = LD8(bpb[0], o); b1C = LD8(bpb[1], o); b2C = LD8(bpb[2], o); b3C = LD8(bpb[3], o);
            a0 = __builtin_amdgcn_mfma_f32_16x16x32_bf16(aN, b0N, a0, 0, 0, 0);
            a1 = __builtin_amdgcn_mfma_f32_16x16x32_bf16(aN, b1N, a1, 0, 0, 0);
            a2 = __builtin_amdgcn_mfma_f32_16x16x32_bf16(aN, b2N, a2, 0, 0, 0);
            a3 = __builtin_amdgcn_mfma_f32_16x16x32_bf16(aN, b3N, a3, 0, 0, 0);
            if (i + 3 < KLP / 32) {
                int o2 = (i + 3) * 32;
                aN = LD8(apb, o2); b0N = LD8(bpb[0], o2); b1N = LD8(bpb[1], o2); b2N = LD8(bpb[2], o2); b3N = LD8(bpb[3], o2);
            }
        }
        a0 = __builtin_amdgcn_mfma_f32_16x16x32_bf16(aC, b0C, a0, 0, 0, 0);
        a1 = __builtin_amdgcn_mfma_f32_16x16x32_bf16(aC, b1C, a1, 0, 0, 0);
        a2 = __builtin_amdgcn_mfma_f32_16x16x32_bf16(aC, b2C, a2, 0, 0, 0);
        a3 = __builtin_amdgcn_mfma_f32_16x16x32_bf16(aC, b3C, a3, 0, 0, 0);
        // KLP/32 = 47 odd: last N-set unused (i ends at 46, one tail iter)

        // fold: per row r (= quad*4+r), block-local max / sumexp / target over 64 cols
#pragma unroll
        for (int r = 0; r < 4; ++r) {
            float v0 = a0[r] + bs[0];
            float v1 = a1[r] + bs[1];
            float v2 = a2[r] + bs[2];
            float v3 = a3[r] + bs[3];
            if (colv[0] >= VOCAB) v0 = -1e30f;
            if (colv[1] >= VOCAB) v1 = -1e30f;
            if (colv[2] >= VOCAB) v2 = -1e30f;
            if (colv[3] >= VOCAB) v3 = -1e30f;
            int row = row_base + quad * 4 + r;
            int t = y[row];
            float tv = -1e30f;
            if (colv[0] == t) tv = v0;
            if (colv[1] == t) tv = v1;
            if (colv[2] == t) tv = v2;
            if (colv[3] == t) tv = v3;
            float mx = fmaxf(fmaxf(v0, v1), fmaxf(v2, v3));
#pragma unroll
            for (int d = 1; d < 16; d <<= 1) mx = fmaxf(mx, __shfl_xor(mx, d, 64));
            float sum = expf(v0 - mx) + expf(v1 - mx) + expf(v2 - mx) + expf(v3 - mx);
#pragma unroll
            for (int d = 1; d < 16; d <<= 1) sum += __shfl_xor(sum, d, 64);
#pragma unroll
            for (int d = 1; d < 16; d <<= 1) tv = fmaxf(tv, __shfl_xor(tv, d, 64));
            if (l16 == 0) {
                partials[(size_t)row * NBLK + nb] = make_float2(mx, sum);
                if (tv > -5e29f) tgtlog[row] = tv;
            }
        }
    }
}

// ---- combine per-block partials -> nll per row; one wave per row ----
__global__ __launch_bounds__(64) void nll_reduce(const float2* __restrict__ partials,
                                                 const float* __restrict__ tgtlog,
                                                 float* __restrict__ nll) {
    int row = blockIdx.x;
    int lane = threadIdx.x;
    float2 loc[3];
    int cnt = 0;
    float m = -1e30f;
    for (int i = lane; i < NBLK; i += 64) {
        float2 p = partials[(size_t)row * NBLK + i];
        loc[cnt++] = p;
        m = fmaxf(m, p.x);
    }
#pragma unroll
    for (int d = 1; d < 64; d <<= 1) m = fmaxf(m, __shfl_xor(m, d, 64));
    float s = 0.f;
    for (int j = 0; j < cnt; ++j) s += loc[j].y * expf(loc[j].x - m);
#pragma unroll
    for (int d = 1; d < 64; d <<= 1) s += __shfl_xor(s, d, 64);
    if (lane == 0) nll[row] = -(tgtlog[row] - m - logf(s));
}

__global__ __launch_bounds__(256) void loss_kernel(const float* __restrict__ nll,
                                                   float* __restrict__ out) {
    __shared__ float red[256];
    int tid = threadIdx.x;
    float s = 0.f;
    for (int i = tid; i < TT * BB; i += 256) s += nll[i];
    red[tid] = s; __syncthreads();
    for (int st = 128; st > 0; st >>= 1) { if (tid < st) red[tid] += red[tid + st]; __syncthreads(); }
    if (tid == 0) out[0] = red[0] / (float)BB;
}

extern "C" void kernel_launch(void* const* d_in, const int* in_sizes, int n_in,
                              void* d_out, int out_size, void* d_ws, size_t ws_size,
                              hipStream_t stream) {
    const int*   x   = (const int*)d_in[0];
    const int*   y   = (const int*)d_in[1];
    const float* emb = (const float*)d_in[2];
    const float* W0  = (const float*)d_in[3];
    const float* b0  = (const float*)d_in[4];
    const float* W1  = (const float*)d_in[5];
    const float* b1  = (const float*)d_in[6];
    const float* sw  = (const float*)d_in[7];
    const float* sb  = (const float*)d_in[8];
    float* out = (float*)d_out;

    // ---- workspace layout; total ~128 MB ----
    char* p = (char*)d_ws;
    unsigned short* A0   = (unsigned short*)p; p += (size_t)TT * BB * KT * 2;   // 13,475,840
    unsigned short* A1   = (unsigned short*)p; p += (size_t)2 * BB * KT * 2;    //    770,048
    unsigned short* outs = (unsigned short*)p; p += (size_t)TT * BB * KLP * 2;  //  6,737,920
    float* c0 = (float*)p; p += (size_t)BB * HID * 4;
    float* c1 = (float*)p; p += (size_t)BB * HID * 4;
    size_t zero_bytes = (size_t)(p - (char*)d_ws);
    unsigned short* WbT0 = (unsigned short*)p; p += (size_t)6000 * KT * 2;      // 36,096,000
    unsigned short* WbT1 = (unsigned short*)p; p += (size_t)6000 * KT * 2;      // 36,096,000
    unsigned short* swT  = (unsigned short*)p; p += (size_t)VOCAB * KLP * 2;    // 30,080,000
    float2* partials = (float2*)p; p += (size_t)TT * BB * NBLK * 8;             //  2,813,440
    float* tgtlog = (float*)p; p += (size_t)TT * BB * 4;
    float* nll    = (float*)p;

    hipMemsetAsync(d_ws, 0, zero_bytes, stream);

    dim3 cblk(32, 8);
    convT<<<dim3(188, 94), cblk, 0, stream>>>(W0, WbT0, 3000, 6000, KT);
    convT<<<dim3(188, 94), cblk, 0, stream>>>(W1, WbT1, 3000, 6000, KT);
    convT<<<dim3(313, 47), cblk, 0, stream>>>(sw, swT, HID, VOCAB, KLP);

    embed_kernel<<<TT * BB, 256, 0, stream>>>(x, emb, A0);

    for (int t = 0; t < TT; ++t) {
        unsigned short* A0t = A0 + (size_t)t * BB * KT;
        unsigned short* A1c = A1 + (size_t)(t & 1) * BB * KT;
        unsigned short* A1n = A1 + (size_t)((t + 1) & 1) * BB * KT;
        unsigned short* h0next = (t < TT - 1) ? (A0 + (size_t)(t + 1) * BB * KT + EMB) : nullptr;
        lstm_fused<<<94, 1024, 0, stream>>>(A0t, WbT0, b0, c0, A1c, KT, h0next, KT);
        lstm_fused<<<94, 1024, 0, stream>>>(A1c, WbT1, b1, c1, A1n + HID, KT,
                                            outs + (size_t)t * BB * KLP, KLP);
    }

    logits_flash<<<dim3(NBLK, 7), 256, 0, stream>>>(outs, swT, sb, y, partials, tgtlog);
    nll_reduce<<<TT * BB, 64, 0, stream>>>(partials, tgtlog, nll);
    loss_kernel<<<1, 256, 0, stream>>>(nll, out);
}

// Round 4
// 2376.365 us; speedup vs baseline: 2.1317x; 2.1317x over previous
//
#include <hip/hip_runtime.h>
#include <math.h>

#define TT 35
#define BB 64
#define EMB 1500
#define HID 1500
#define VOCAB 10000
#define KT 3072          // EMB+HID padded to x128 (4 k-groups x 24 chunks x 32)
#define KG 768           // K per k-group
#define NCH 24           // chunks of 32 per k-group
#define KLP 1504         // HID padded to x32 (logits K)
#define NBLK 157         // vocab n-blocks of 64
#define MBLK 35          // 2240/64 row blocks
#define FORGET_BIAS 1.0f

typedef __bf16 bf16x8 __attribute__((ext_vector_type(8)));
typedef float f32x4 __attribute__((ext_vector_type(4)));

__device__ __forceinline__ unsigned short f2bf(float f) {
    unsigned int u = __builtin_bit_cast(unsigned int, f);
    u += 0x7fffu + ((u >> 16) & 1u);           // RNE
    return (unsigned short)(u >> 16);
}
__device__ __forceinline__ float sigmoidf_(float x) { return 1.0f / (1.0f + expf(-x)); }

#define GLOAD_LDS16(gp, lp) __builtin_amdgcn_global_load_lds( \
    (const __attribute__((address_space(1))) void*)(gp),      \
    (__attribute__((address_space(3))) void*)(lp), 16, 0, 0)

// ---- W (K x N fp32) -> WT (N x KP bf16), zero-fill k in [K,KP) ----
__global__ __launch_bounds__(256) void convT(const float* __restrict__ W,
                                             unsigned short* __restrict__ WT,
                                             int K, int N, int KP) {
    __shared__ float tile[32][33];
    int tx = threadIdx.x, ty = threadIdx.y;    // 32 x 8
    int n0 = blockIdx.x * 32, k0 = blockIdx.y * 32;
#pragma unroll
    for (int i = 0; i < 4; ++i) {
        int k = k0 + ty + 8 * i, n = n0 + tx;
        tile[ty + 8 * i][tx] = (k < K && n < N) ? W[(size_t)k * N + n] : 0.f;
    }
    __syncthreads();
#pragma unroll
    for (int i = 0; i < 4; ++i) {
        int n = n0 + ty + 8 * i, k = k0 + tx;
        if (n < N) WT[(size_t)n * KP + k] = f2bf(tile[tx][ty + 8 * i]);
    }
}

// ---- embedding gather -> bf16 into per-step A0 buffers (cols 0..1499) ----
__global__ __launch_bounds__(256) void embed_kernel(const int* __restrict__ x,
                                                    const float* __restrict__ emb,
                                                    unsigned short* __restrict__ A0) {
    int tok = blockIdx.x;                       // t*BB + b (t-major)
    int v = x[tok];
    const float* src = emb + (size_t)v * EMB;
    unsigned short* dst = A0 + (size_t)tok * KT;
    for (int i = threadIdx.x; i < EMB; i += 256) dst[i] = f2bf(src[i]);
}

// ---- fused LSTM step, m97-style LDS staging via global_load_lds ----
// grid 94 (16 hidden cols each), block 1024 = 16 waves: kg = wv>>2 (k-group), mt = wv&3 (m-tile)
// Per chunk (BK=32): each kg stages A-tile 64x32 + B-tile 64x32 (4KB each) double-buffered.
// LDS: stage [buf][ab][kg] 4KB each = 64KB exactly; epilogue reduction overlays it.
__global__ __launch_bounds__(1024) void lstm_fused(const unsigned short* __restrict__ A,   // 64 x KT
                                                   const unsigned short* __restrict__ WT,  // 6000 x KT
                                                   const float* __restrict__ bias,         // 6000
                                                   float* __restrict__ cst,                // 64 x HID
                                                   unsigned short* __restrict__ d1, int s1,
                                                   unsigned short* __restrict__ d2, int s2) {
    __shared__ __align__(16) unsigned char smem[65536];
    int tid = threadIdx.x;
    int wv = tid >> 6, lane = tid & 63;
    int mt = wv & 3, kg = wv >> 2;
    int quad = lane >> 4, l16 = lane & 15;
    int nb = blockIdx.x;
    int col = nb * 16 + l16;

    // ---- staging setup: this wave issues instrs q0=2mt, q1=2mt+1 for its kg ----
    int rr = lane >> 2, p = lane & 3;
    int sp = p ^ (rr & 3);                      // XOR swizzle on the GLOBAL side
    int kbase = kg * KG;
    int q0 = mt * 2, q1 = q0 + 1;
    const unsigned short* gp[2];
    int ldsoff[2];
#pragma unroll
    for (int ii = 0; ii < 2; ++ii) {
        int q = ii ? q1 : q0;
        if (q < 4) {                            // A rows 16q+rr
            gp[ii] = A + (size_t)(16 * q + rr) * KT + kbase + sp * 8;
        } else {                                // B: gate g=q-4, col index rr
            int g = q - 4;
            int ci = nb * 16 + rr; if (ci > HID - 1) ci = HID - 1;   // clamp pad cols
            gp[ii] = WT + (size_t)(g * HID + ci) * KT + kbase + sp * 8;
        }
        ldsoff[ii] = ((q >> 2) * 4 + kg) * 4096 + (q & 3) * 1024;    // + buf*32768
    }

    int swz = (quad ^ (l16 & 3)) * 16;
    int aoff = (0 * 4 + kg) * 4096 + (mt * 16 + l16) * 64 + swz;     // + buf*32768
    int boff = (1 * 4 + kg) * 4096 + l16 * 64 + swz;                 // + gate*1024 + buf*32768

    f32x4 acc0 = {0.f,0.f,0.f,0.f}, acc1 = acc0, acc2 = acc0, acc3 = acc0;

    // prologue: stage chunk 0 into buf 0
    GLOAD_LDS16(gp[0], smem + ldsoff[0]);
    GLOAD_LDS16(gp[1], smem + ldsoff[1]);
    __syncthreads();

    for (int c = 0; c < NCH; ++c) {
        int buf = c & 1;
        if (c + 1 < NCH) {                      // stage next chunk into other buffer
            int nb2 = (buf ^ 1) * 32768;
            GLOAD_LDS16(gp[0] + (c + 1) * 32, smem + nb2 + ldsoff[0]);
            GLOAD_LDS16(gp[1] + (c + 1) * 32, smem + nb2 + ldsoff[1]);
        }
        const unsigned char* base = smem + buf * 32768;
        bf16x8 a  = *(const bf16x8*)(base + aoff);
        bf16x8 b0 = *(const bf16x8*)(base + boff);
        bf16x8 b1 = *(const bf16x8*)(base + boff + 1024);
        bf16x8 b2 = *(const bf16x8*)(base + boff + 2048);
        bf16x8 b3 = *(const bf16x8*)(base + boff + 3072);
        acc0 = __builtin_amdgcn_mfma_f32_16x16x32_bf16(a, b0, acc0, 0, 0, 0);
        acc1 = __builtin_amdgcn_mfma_f32_16x16x32_bf16(a, b1, acc1, 0, 0, 0);
        acc2 = __builtin_amdgcn_mfma_f32_16x16x32_bf16(a, b2, acc2, 0, 0, 0);
        acc3 = __builtin_amdgcn_mfma_f32_16x16x32_bf16(a, b3, acc3, 0, 0, 0);
        __syncthreads();                        // drains stage(c+1); protects buf reuse
    }

    // ---- epilogue: k-group reduction through LDS (overlays stage memory) ----
    float* red = (float*)smem;                  // [12 waves][64 lanes][16]
    if (kg > 0) {
        int w = (kg - 1) * 4 + mt;
#pragma unroll
        for (int r = 0; r < 4; ++r) {
            red[(w * 64 + lane) * 16 + r]      = acc0[r];
            red[(w * 64 + lane) * 16 + 4 + r]  = acc1[r];
            red[(w * 64 + lane) * 16 + 8 + r]  = acc2[r];
            red[(w * 64 + lane) * 16 + 12 + r] = acc3[r];
        }
    }
    __syncthreads();
    if (kg == 0) {
#pragma unroll
        for (int k2 = 0; k2 < 3; ++k2) {
            int w = k2 * 4 + mt;
#pragma unroll
            for (int r = 0; r < 4; ++r) {
                acc0[r] += red[(w * 64 + lane) * 16 + r];
                acc1[r] += red[(w * 64 + lane) * 16 + 4 + r];
                acc2[r] += red[(w * 64 + lane) * 16 + 8 + r];
                acc3[r] += red[(w * 64 + lane) * 16 + 12 + r];
            }
        }
        if (col < HID) {
            float bi = bias[col], bj = bias[HID + col];
            float bf_ = bias[2 * HID + col], bo = bias[3 * HID + col];
#pragma unroll
            for (int r = 0; r < 4; ++r) {
                int row = mt * 16 + quad * 4 + r;
                float zi = acc0[r] + bi;
                float zj = acc1[r] + bj;
                float zf = acc2[r] + bf_;
                float zo = acc3[r] + bo;
                int ci = row * HID + col;
                float cn = cst[ci] * sigmoidf_(zf + FORGET_BIAS) + sigmoidf_(zi) * tanhf(zj);
                float hn = tanhf(cn) * sigmoidf_(zo);
                cst[ci] = cn;
                unsigned short hb = f2bf(hn);
                d1[(size_t)row * s1 + col] = hb;
                if (d2) d2[(size_t)row * s2 + col] = hb;
            }
        }
    }
}

// ---- logits + flash fold: grid (MBLK, NBLK) m-fastest; block 256 = 4 waves x 16 rows ----
// Round-2 proven GEMM body (plain loads, low VGPR); fold epilogue -> (max,sumexp) partials.
__global__ __launch_bounds__(256) void logits_fold(const unsigned short* __restrict__ A,   // 2240 x KLP
                                                   const unsigned short* __restrict__ WT,  // 10000 x KLP
                                                   const float* __restrict__ sb,
                                                   const int* __restrict__ y,
                                                   float2* __restrict__ partials,          // [2240][NBLK]
                                                   float* __restrict__ tgtlog) {           // [2240]
    int tid = threadIdx.x;
    int wv = tid >> 6, lane = tid & 63;
    int quad = lane >> 4, l16 = lane & 15;
    int row0 = blockIdx.x * 64 + wv * 16;
    int nb = blockIdx.y;
    int n0 = nb * 64;
    f32x4 acc[4];
#pragma unroll
    for (int s = 0; s < 4; ++s) acc[s] = (f32x4){0.f, 0.f, 0.f, 0.f};
    const unsigned short* ap = A + (size_t)(row0 + l16) * KLP + quad * 8;
    const unsigned short* bp[4];
    int colv[4]; float bs[4];
#pragma unroll
    for (int s = 0; s < 4; ++s) {
        int c = n0 + s * 16 + l16;
        colv[s] = c;
        int cc = (c < VOCAB) ? c : (VOCAB - 1);
        bp[s] = WT + (size_t)cc * KLP + quad * 8;
        bs[s] = sb[cc];
    }
    for (int it = 0; it < KLP / 32; ++it) {
        bf16x8 a  = *(const bf16x8*)ap;
        bf16x8 b0 = *(const bf16x8*)bp[0];
        bf16x8 b1 = *(const bf16x8*)bp[1];
        bf16x8 b2 = *(const bf16x8*)bp[2];
        bf16x8 b3 = *(const bf16x8*)bp[3];
        acc[0] = __builtin_amdgcn_mfma_f32_16x16x32_bf16(a, b0, acc[0], 0, 0, 0);
        acc[1] = __builtin_amdgcn_mfma_f32_16x16x32_bf16(a, b1, acc[1], 0, 0, 0);
        acc[2] = __builtin_amdgcn_mfma_f32_16x16x32_bf16(a, b2, acc[2], 0, 0, 0);
        acc[3] = __builtin_amdgcn_mfma_f32_16x16x32_bf16(a, b3, acc[3], 0, 0, 0);
        ap += 32; bp[0] += 32; bp[1] += 32; bp[2] += 32; bp[3] += 32;
    }
#pragma unroll
    for (int r = 0; r < 4; ++r) {
        float v0 = acc[0][r] + bs[0];
        float v1 = acc[1][r] + bs[1];
        float v2 = acc[2][r] + bs[2];
        float v3 = acc[3][r] + bs[3];
        if (colv[0] >= VOCAB) v0 = -1e30f;
        if (colv[1] >= VOCAB) v1 = -1e30f;
        if (colv[2] >= VOCAB) v2 = -1e30f;
        if (colv[3] >= VOCAB) v3 = -1e30f;
        int row = row0 + quad * 4 + r;
        int t = y[row];
        float tv = -1e30f;
        if (colv[0] == t) tv = v0;
        if (colv[1] == t) tv = v1;
        if (colv[2] == t) tv = v2;
        if (colv[3] == t) tv = v3;
        float mx = fmaxf(fmaxf(v0, v1), fmaxf(v2, v3));
#pragma unroll
        for (int d = 1; d < 16; d <<= 1) mx = fmaxf(mx, __shfl_xor(mx, d, 64));
        float sum = expf(v0 - mx) + expf(v1 - mx) + expf(v2 - mx) + expf(v3 - mx);
#pragma unroll
        for (int d = 1; d < 16; d <<= 1) sum += __shfl_xor(sum, d, 64);
#pragma unroll
        for (int d = 1; d < 16; d <<= 1) tv = fmaxf(tv, __shfl_xor(tv, d, 64));
        if (l16 == 0) {
            partials[(size_t)row * NBLK + nb] = make_float2(mx, sum);
            if (tv > -5e29f) tgtlog[row] = tv;
        }
    }
}

// ---- combine per-block partials -> nll per row; one wave per row ----
__global__ __launch_bounds__(64) void nll_reduce(const float2* __restrict__ partials,
                                                 const float* __restrict__ tgtlog,
                                                 float* __restrict__ nll) {
    int row = blockIdx.x;
    int lane = threadIdx.x;
    float2 loc[3];
    int cnt = 0;
    float m = -1e30f;
    for (int i = lane; i < NBLK; i += 64) {
        float2 p = partials[(size_t)row * NBLK + i];
        loc[cnt++] = p;
        m = fmaxf(m, p.x);
    }
#pragma unroll
    for (int d = 1; d < 64; d <<= 1) m = fmaxf(m, __shfl_xor(m, d, 64));
    float s = 0.f;
    for (int j = 0; j < cnt; ++j) s += loc[j].y * expf(loc[j].x - m);
#pragma unroll
    for (int d = 1; d < 64; d <<= 1) s += __shfl_xor(s, d, 64);
    if (lane == 0) nll[row] = -(tgtlog[row] - m - logf(s));
}

__global__ __launch_bounds__(256) void loss_kernel(const float* __restrict__ nll,
                                                   float* __restrict__ out) {
    __shared__ float red[256];
    int tid = threadIdx.x;
    float s = 0.f;
    for (int i = tid; i < TT * BB; i += 256) s += nll[i];
    red[tid] = s; __syncthreads();
    for (int st = 128; st > 0; st >>= 1) { if (tid < st) red[tid] += red[tid + st]; __syncthreads(); }
    if (tid == 0) out[0] = red[0] / (float)BB;
}

extern "C" void kernel_launch(void* const* d_in, const int* in_sizes, int n_in,
                              void* d_out, int out_size, void* d_ws, size_t ws_size,
                              hipStream_t stream) {
    const int*   x   = (const int*)d_in[0];
    const int*   y   = (const int*)d_in[1];
    const float* emb = (const float*)d_in[2];
    const float* W0  = (const float*)d_in[3];
    const float* b0  = (const float*)d_in[4];
    const float* W1  = (const float*)d_in[5];
    const float* b1  = (const float*)d_in[6];
    const float* sw  = (const float*)d_in[7];
    const float* sb  = (const float*)d_in[8];
    float* out = (float*)d_out;

    // ---- workspace layout; total ~129 MB ----
    char* p = (char*)d_ws;
    unsigned short* A0   = (unsigned short*)p; p += (size_t)TT * BB * KT * 2;   // 13,762,560
    unsigned short* A1   = (unsigned short*)p; p += (size_t)2 * BB * KT * 2;    //    786,432
    unsigned short* outs = (unsigned short*)p; p += (size_t)TT * BB * KLP * 2;  //  6,737,920
    float* c0 = (float*)p; p += (size_t)BB * HID * 4;
    float* c1 = (float*)p; p += (size_t)BB * HID * 4;
    size_t zero_bytes = (size_t)(p - (char*)d_ws);                              // 22,054,912
    unsigned short* WbT0 = (unsigned short*)p; p += (size_t)6000 * KT * 2;      // 36,864,000
    unsigned short* WbT1 = (unsigned short*)p; p += (size_t)6000 * KT * 2;      // 36,864,000
    unsigned short* swT  = (unsigned short*)p; p += (size_t)VOCAB * KLP * 2;    // 30,080,000
    float2* partials = (float2*)p; p += (size_t)TT * BB * NBLK * 8;             //  2,813,440
    float* tgtlog = (float*)p; p += (size_t)TT * BB * 4;
    float* nll    = (float*)p;

    hipMemsetAsync(d_ws, 0, zero_bytes, stream);

    dim3 cblk(32, 8);
    convT<<<dim3(188, 96), cblk, 0, stream>>>(W0, WbT0, 3000, 6000, KT);
    convT<<<dim3(188, 96), cblk, 0, stream>>>(W1, WbT1, 3000, 6000, KT);
    convT<<<dim3(313, 47), cblk, 0, stream>>>(sw, swT, HID, VOCAB, KLP);

    embed_kernel<<<TT * BB, 256, 0, stream>>>(x, emb, A0);

    for (int t = 0; t < TT; ++t) {
        unsigned short* A0t = A0 + (size_t)t * BB * KT;
        unsigned short* A1c = A1 + (size_t)(t & 1) * BB * KT;
        unsigned short* A1n = A1 + (size_t)((t + 1) & 1) * BB * KT;
        unsigned short* h0next = (t < TT - 1) ? (A0 + (size_t)(t + 1) * BB * KT + EMB) : nullptr;
        lstm_fused<<<94, 1024, 0, stream>>>(A0t, WbT0, b0, c0, A1c, KT, h0next, KT);
        lstm_fused<<<94, 1024, 0, stream>>>(A1c, WbT1, b1, c1, A1n + HID, KT,
                                            outs + (size_t)t * BB * KLP, KLP);
    }

    logits_fold<<<dim3(MBLK, NBLK), 256, 0, stream>>>(outs, swT, sb, y, partials, tgtlog);
    nll_reduce<<<TT * BB, 64, 0, stream>>>(partials, tgtlog, nll);
    loss_kernel<<<1, 256, 0, stream>>>(nll, out);
}